// Round 1
// baseline (15807.169 us; speedup 1.0000x reference)
//
#include <hip/hip_runtime.h>
#include <math.h>

#define N_NODE 512
#define BATCH  16
#define HID    64
#define T_IN   12
#define T_OUT  12
#define NB     (N_NODE * BATCH)   /* 8192 rows (n*16+b) */
#define EPSV   1e-6f

// ---------------------------------------------------------------------------
// Segmented-K descriptor for the linear (dconv concat @ W) GEMMs.
// Input row (n,b) feature k comes from segment s: p[s] + row*stride[s] + (k - k0_of_s)
// and multiplies weight row wrow[s] + (k - k0_of_s).
// ---------------------------------------------------------------------------
struct Segs {
    const float* p[10];
    int stride[10];
    int len[10];
    int wrow[10];
    int n;
};

// ---------------------------------------------------------------------------
// Random-walk normalization:  Wf = A / (rowsum+eps);  Wb[i,j] = A[j,i]/(colsum_i+eps)
// ---------------------------------------------------------------------------
__global__ void sums_kernel(const float* __restrict__ A, float* __restrict__ rs,
                            float* __restrict__ cs) {
    int i = blockIdx.x;
    int t = threadIdx.x;
    __shared__ float s1[256], s2[256];
    float a = A[i * 512 + t] + A[i * 512 + t + 256];
    float b = A[t * 512 + i] + A[(t + 256) * 512 + i];
    s1[t] = a; s2[t] = b;
    __syncthreads();
    for (int off = 128; off > 0; off >>= 1) {
        if (t < off) { s1[t] += s1[t + off]; s2[t] += s2[t + off]; }
        __syncthreads();
    }
    if (t == 0) { rs[i] = s1[0]; cs[i] = s2[0]; }
}

__global__ void fill_kernel(const float* __restrict__ A, const float* __restrict__ rs,
                            const float* __restrict__ cs, float* __restrict__ Wf,
                            float* __restrict__ Wb) {
    int i = blockIdx.x;
    float irs = 1.0f / (rs[i] + EPSV);
    float ics = 1.0f / (cs[i] + EPSV);
    for (int j = threadIdx.x; j < 512; j += 256) {
        Wf[i * 512 + j] = A[i * 512 + j] * irs;
        Wb[i * 512 + j] = A[j * 512 + i] * ics;
    }
}

// ---------------------------------------------------------------------------
// Concat builders: XC layout (N, B, F) flat = row (n*16+b) * F + c
// ---------------------------------------------------------------------------
__global__ void concat0_kernel(float* __restrict__ XC, const float* __restrict__ x,
                               int t, const float* __restrict__ di, int use_di,
                               const float* __restrict__ h0) {
    int idx = blockIdx.x * 256 + threadIdx.x;     // over NB*65
    if (idx >= NB * 65) return;
    int c = idx % 65;
    int row = idx / 65;                            // n*16 + b
    float v;
    if (c == 0) {
        int n = row >> 4, b = row & 15;
        v = use_di ? di[row] : x[(b * T_IN + t) * N_NODE + n];
    } else {
        v = h0[row * 64 + (c - 1)];
    }
    XC[idx] = v;
}

__global__ void concat1_kernel(float* __restrict__ XC, const float* __restrict__ h0,
                               const float* __restrict__ h1) {
    int idx = blockIdx.x * 256 + threadIdx.x;     // over NB*128
    int c = idx & 127;
    int row = idx >> 7;
    XC[idx] = (c < 64) ? h0[row * 64 + c] : h1[row * 64 + (c - 64)];
}

// ---------------------------------------------------------------------------
// Graph-hop GEMM: Y(512 x ncols) = Wm(512x512) @ X(512 x ncols)
// blockIdx.z selects (W0,X0,Y0) vs (W1,X1,Y1) so fwd+bwd hops share a launch.
// 64x64 tile, 256 threads, 4x4 micro-tile, Kt=16, K=512.
// ---------------------------------------------------------------------------
__global__ __launch_bounds__(256) void ghop_kernel(
    const float* __restrict__ W0, const float* __restrict__ W1,
    const float* __restrict__ X0, const float* __restrict__ X1,
    float* __restrict__ Y0, float* __restrict__ Y1, int ncols) {
    const float* Wm; const float* X; float* Y;
    if (blockIdx.z == 0) { Wm = W0; X = X0; Y = Y0; }
    else                 { Wm = W1; X = X1; Y = Y1; }

    int row0 = blockIdx.y * 64;
    int col0 = blockIdx.x * 64;
    int tid = threadIdx.x;
    int tx = tid & 15, ty = tid >> 4;
    int kkA = tid & 15, rrA = tid >> 4;
    int ccB = tid & 63, kkB = tid >> 6;

    __shared__ float As[16][68];   // k-major, padded pitch (68*4 bytes, 16B aligned)
    __shared__ float Bs[16][68];

    float acc[4][4] = {};

    for (int k0 = 0; k0 < 512; k0 += 16) {
#pragma unroll
        for (int p4 = 0; p4 < 4; ++p4) {
            int r = rrA + p4 * 16;
            As[kkA][r] = Wm[(row0 + r) * 512 + k0 + kkA];
        }
#pragma unroll
        for (int p4 = 0; p4 < 4; ++p4) {
            int k = kkB + p4 * 4;
            int c = col0 + ccB;
            Bs[k][ccB] = (c < ncols) ? X[(k0 + k) * ncols + c] : 0.0f;
        }
        __syncthreads();
#pragma unroll
        for (int k = 0; k < 16; ++k) {
            const float4 a4 = *(const float4*)&As[k][ty * 4];
            const float4 b4 = *(const float4*)&Bs[k][tx * 4];
            float av[4] = { a4.x, a4.y, a4.z, a4.w };
            float bv[4] = { b4.x, b4.y, b4.z, b4.w };
#pragma unroll
            for (int i = 0; i < 4; ++i)
#pragma unroll
                for (int j = 0; j < 4; ++j)
                    acc[i][j] = fmaf(av[i], bv[j], acc[i][j]);
        }
        __syncthreads();
    }

#pragma unroll
    for (int i = 0; i < 4; ++i) {
        int row = row0 + ty * 4 + i;
#pragma unroll
        for (int j = 0; j < 4; ++j) {
            int col = col0 + tx * 4 + j;
            if (col < ncols) Y[row * ncols + col] = acc[i][j];
        }
    }
}

// ---------------------------------------------------------------------------
// Segmented-K 64-row x 64-col linear tile core (shared by rz / n kernels)
// ---------------------------------------------------------------------------
__device__ __forceinline__ void lin_tile(const Segs& segs, const float* __restrict__ W,
                                         int row0, int tid, float acc[4][4],
                                         float (*As)[68], float (*Ws)[68]) {
    int kkA = tid & 15, rrA = tid >> 4;
    int ccW = tid & 63, kkW = tid >> 6;
    int tx = tid & 15, ty = tid >> 4;

    for (int s = 0; s < segs.n; ++s) {
        const float* p = segs.p[s];
        int stride = segs.stride[s];
        int len = segs.len[s];
        int wr = segs.wrow[s];
        for (int k0 = 0; k0 < len; k0 += 16) {
            int kt = len - k0; if (kt > 16) kt = 16;
#pragma unroll
            for (int p4 = 0; p4 < 4; ++p4) {
                int r = rrA + p4 * 16;
                As[kkA][r] = (kkA < kt) ? p[(row0 + r) * stride + k0 + kkA] : 0.0f;
            }
#pragma unroll
            for (int p4 = 0; p4 < 4; ++p4) {
                int k = kkW + p4 * 4;
                Ws[k][ccW] = (k < kt) ? W[(wr + k0 + k) * 64 + ccW] : 0.0f;
            }
            __syncthreads();
#pragma unroll
            for (int k = 0; k < 16; ++k) {
                const float4 a4 = *(const float4*)&As[k][ty * 4];
                const float4 b4 = *(const float4*)&Ws[k][tx * 4];
                float av[4] = { a4.x, a4.y, a4.z, a4.w };
                float bv[4] = { b4.x, b4.y, b4.z, b4.w };
#pragma unroll
                for (int i = 0; i < 4; ++i)
#pragma unroll
                    for (int j = 0; j < 4; ++j)
                        acc[i][j] = fmaf(av[i], bv[j], acc[i][j]);
            }
            __syncthreads();
        }
    }
}

// r/z gates: grid (NB/64, 2). y==0: G = sigmoid(pre_r)*h ; y==1: Z = sigmoid(pre_z)
__global__ __launch_bounds__(256) void lin_rz_kernel(
    Segs segs, const float* __restrict__ Wr, const float* __restrict__ br,
    const float* __restrict__ Wz, const float* __restrict__ bz,
    const float* __restrict__ h, float* __restrict__ G, float* __restrict__ Z) {
    __shared__ float As[16][68], Ws[16][68];
    int row0 = blockIdx.x * 64;
    int tid = threadIdx.x;
    const float* W = (blockIdx.y == 0) ? Wr : Wz;
    const float* bias = (blockIdx.y == 0) ? br : bz;
    float acc[4][4] = {};
    lin_tile(segs, W, row0, tid, acc, As, Ws);
    int tx = tid & 15, ty = tid >> 4;
#pragma unroll
    for (int i = 0; i < 4; ++i) {
        int row = row0 + ty * 4 + i;
#pragma unroll
        for (int j = 0; j < 4; ++j) {
            int col = tx * 4 + j;
            float pre = acc[i][j] + bias[col];
            float sg = 1.0f / (1.0f + __expf(-pre));
            if (blockIdx.y == 0) G[row * 64 + col] = sg * h[row * 64 + col];
            else                 Z[row * 64 + col] = sg;
        }
    }
}

// n gate + GRU state update (in place on h)
__global__ __launch_bounds__(256) void lin_n_kernel(
    Segs segs, const float* __restrict__ Wn, const float* __restrict__ bn,
    const float* __restrict__ Z, float* __restrict__ h) {
    __shared__ float As[16][68], Ws[16][68];
    int row0 = blockIdx.x * 64;
    int tid = threadIdx.x;
    float acc[4][4] = {};
    lin_tile(segs, Wn, row0, tid, acc, As, Ws);
    int tx = tid & 15, ty = tid >> 4;
#pragma unroll
    for (int i = 0; i < 4; ++i) {
        int row = row0 + ty * 4 + i;
#pragma unroll
        for (int j = 0; j < 4; ++j) {
            int col = tx * 4 + j;
            int idx = row * 64 + col;
            float nn = tanhf(acc[i][j] + bn[col]);
            float z = Z[idx];
            float hv = h[idx];
            h[idx] = (1.0f - z) * hv + z * nn;
        }
    }
}

// Decoder projection: y = h1 @ Wp + bp ; writes output slice and next di
__global__ void proj_kernel(const float* __restrict__ h1, const float* __restrict__ Wp,
                            const float* __restrict__ bp, float* __restrict__ out,
                            float* __restrict__ di, int t) {
    int idx = blockIdx.x * 256 + threadIdx.x;   // over NB
    if (idx >= NB) return;
    float s = bp[0];
    const float4* hp = (const float4*)&h1[idx * 64];
#pragma unroll
    for (int c4 = 0; c4 < 16; ++c4) {
        float4 hv = hp[c4];
        s += hv.x * Wp[c4 * 4 + 0] + hv.y * Wp[c4 * 4 + 1]
           + hv.z * Wp[c4 * 4 + 2] + hv.w * Wp[c4 * 4 + 3];
    }
    int n = idx >> 4, b = idx & 15;
    out[(b * T_OUT + t) * N_NODE + n] = s;
    di[idx] = s;
}

// ---------------------------------------------------------------------------
extern "C" void kernel_launch(void* const* d_in, const int* in_sizes, int n_in,
                              void* d_out, int out_size, void* d_ws, size_t ws_size,
                              hipStream_t stream) {
    (void)in_sizes; (void)n_in; (void)out_size; (void)ws_size;
    const float* x   = (const float*)d_in[0];
    const float* A   = (const float*)d_in[1];
    const float* Wg[2][3] = { { (const float*)d_in[2], (const float*)d_in[4], (const float*)d_in[6] },
                              { (const float*)d_in[8], (const float*)d_in[10], (const float*)d_in[12] } };
    const float* bg[2][3] = { { (const float*)d_in[3], (const float*)d_in[5], (const float*)d_in[7] },
                              { (const float*)d_in[9], (const float*)d_in[11], (const float*)d_in[13] } };
    const float* Wp  = (const float*)d_in[14];
    const float* bp  = (const float*)d_in[15];
    float* out = (float*)d_out;

    float* ws = (float*)d_ws;
    size_t off = 0;
    auto alloc = [&](size_t nf) { float* p = ws + off; off += nf; return p; };
    float* Wf   = alloc(512 * 512);
    float* Wb   = alloc(512 * 512);
    float* rs   = alloc(512);
    float* cs   = alloc(512);
    float* XALL = alloc(5ul * NB * 128);   // 5 hop tensors, max F=128
    float* GALL = alloc(5ul * NB * 64);    // g = r*h and its 4 hops
    float* Z    = alloc((size_t)NB * 64);
    float* h0   = alloc((size_t)NB * 64);
    float* h1   = alloc((size_t)NB * 64);
    float* di   = alloc(NB);

    hipMemsetAsync(h0, 0, (size_t)NB * 64 * sizeof(float), stream);
    hipMemsetAsync(h1, 0, (size_t)NB * 64 * sizeof(float), stream);

    sums_kernel<<<512, 256, 0, stream>>>(A, rs, cs);
    fill_kernel<<<512, 256, 0, stream>>>(A, rs, cs, Wf, Wb);

    // Run one DCGRU cell. layer: 0 (F=65) or 1 (F=128). h = state to update.
    auto run_cell = [&](int layer, float* h) {
        const int F = layer ? 128 : 65;
        const size_t NBF = (size_t)NB * F;
        const int ncols = BATCH * F;
        const int ct = (ncols + 63) / 64;
        float* XC  = XALL;
        float* X1F = XALL + NBF;
        float* X2F = XALL + 2 * NBF;
        float* X1B = XALL + 3 * NBF;
        float* X2B = XALL + 4 * NBF;
        const size_t NB64 = (size_t)NB * 64;
        float* G   = GALL;
        float* G1F = GALL + NB64;
        float* G2F = GALL + 2 * NB64;
        float* G1B = GALL + 3 * NB64;
        float* G2B = GALL + 4 * NB64;

        // hops of concat([xl, h])
        ghop_kernel<<<dim3(ct, 8, 2), 256, 0, stream>>>(Wf, Wb, XC, XC, X1F, X1B, ncols);
        ghop_kernel<<<dim3(ct, 8, 2), 256, 0, stream>>>(Wf, Wb, X1F, X1B, X2F, X2B, ncols);

        // r & z gates (r fused into G = r*h)
        Segs srz; srz.n = 5;
        for (int k = 0; k < 5; ++k) {
            srz.p[k] = XALL + k * NBF; srz.stride[k] = F; srz.len[k] = F; srz.wrow[k] = k * F;
        }
        lin_rz_kernel<<<dim3(NB / 64, 2), 256, 0, stream>>>(
            srz, Wg[layer][0], bg[layer][0], Wg[layer][1], bg[layer][1], h, G, Z);

        // hops of g = r*h
        ghop_kernel<<<dim3(16, 8, 2), 256, 0, stream>>>(Wf, Wb, G, G, G1F, G1B, 1024);
        ghop_kernel<<<dim3(16, 8, 2), 256, 0, stream>>>(Wf, Wb, G1F, G1B, G2F, G2B, 1024);

        // n gate + update: input blocks = [xl-part (from XALL hops), g-part (GALL hops)]
        const int Fx = F - 64;   // 1 for layer0, 64 for layer1
        Segs sn; sn.n = 10;
        for (int k = 0; k < 5; ++k) {
            sn.p[2 * k] = XALL + k * NBF; sn.stride[2 * k] = F; sn.len[2 * k] = Fx;
            sn.wrow[2 * k] = k * F;
            sn.p[2 * k + 1] = GALL + k * NB64; sn.stride[2 * k + 1] = 64; sn.len[2 * k + 1] = 64;
            sn.wrow[2 * k + 1] = k * F + Fx;
        }
        lin_n_kernel<<<dim3(NB / 64, 1), 256, 0, stream>>>(sn, Wg[layer][2], bg[layer][2], Z, h);
    };

    auto step = [&](int t_enc, int use_di) {
        concat0_kernel<<<(NB * 65) / 256, 256, 0, stream>>>(XALL, x, t_enc, di, use_di, h0);
        run_cell(0, h0);
        concat1_kernel<<<(NB * 128) / 256, 256, 0, stream>>>(XALL, h0, h1);
        run_cell(1, h1);
    };

    // encoder
    for (int t = 0; t < T_IN; ++t) step(t, 0);
    // decoder
    for (int t = 0; t < T_OUT; ++t) {
        step(t == 0 ? (T_IN - 1) : 0, t == 0 ? 0 : 1);   // step0 uses x[:, -1]
        proj_kernel<<<NB / 256, 256, 0, stream>>>(h1, Wp, bp, out, di, t);
    }
}

// Round 2
// 7376.666 us; speedup vs baseline: 2.1429x; 2.1429x over previous
//
#include <hip/hip_runtime.h>
#include <math.h>

#define T_IN   12
#define T_OUT  12
#define NB     8192          /* 512 nodes x 16 batch, row id = n*16+b */
#define EPSV   1e-6f

// ---------------------------------------------------------------------------
// Segmented-K descriptor for the linear (dconv concat @ W) GEMMs.
// Feature k of lin-row r in segment s lives at p[s] + r*stride[s] + k,
// multiplying weight row wrow[s]+k.
// ---------------------------------------------------------------------------
struct Segs { const float* p[10]; int stride[10]; int len[10]; int wrow[10]; int n; };

// ---------------------------------------------------------------------------
// Hop GEMM job descriptor: Y[z] = M[z] @ X, X addressed as
// X[k, c] = src + k*rs + c*cs.  Two column-segments per launch; selfSrc=1
// means X = M[z] (used to build W^2 once at setup).
// ---------------------------------------------------------------------------
struct HopA {
    const float* M[4];
    const float* src0; const float* src1;
    float* dst0[4]; float* dst1[4];
    int rs0, cs0, ncols0, tiles0;
    int rs1, cs1, ncols1;
    int selfSrc;
};

// ---------------------------------------------------------------------------
// Random-walk normalization
// ---------------------------------------------------------------------------
__global__ void sums_kernel(const float* __restrict__ A, float* __restrict__ rs,
                            float* __restrict__ cs) {
    int i = blockIdx.x;
    int t = threadIdx.x;
    __shared__ float s1[256], s2[256];
    float a = A[i * 512 + t] + A[i * 512 + t + 256];
    float b = A[t * 512 + i] + A[(t + 256) * 512 + i];
    s1[t] = a; s2[t] = b;
    __syncthreads();
    for (int off = 128; off > 0; off >>= 1) {
        if (t < off) { s1[t] += s1[t + off]; s2[t] += s2[t + off]; }
        __syncthreads();
    }
    if (t == 0) { rs[i] = s1[0]; cs[i] = s2[0]; }
}

__global__ void fill_kernel(const float* __restrict__ A, const float* __restrict__ rs,
                            const float* __restrict__ cs, float* __restrict__ Wf,
                            float* __restrict__ Wb) {
    int i = blockIdx.x;
    float irs = 1.0f / (rs[i] + EPSV);
    float ics = 1.0f / (cs[i] + EPSV);
    for (int j = threadIdx.x; j < 512; j += 256) {
        Wf[i * 512 + j] = A[i * 512 + j] * irs;
        Wb[i * 512 + j] = A[j * 512 + i] * ics;
    }
}

// Pre-transpose all encoder x slices: xenc[t][j*16+b] = x[b, t, j]
__global__ void xenc_kernel(const float* __restrict__ x, float* __restrict__ xenc) {
    int idx = blockIdx.x * 256 + threadIdx.x;
    if (idx >= T_IN * NB) return;
    int j = idx & 511;
    int b = (idx >> 9) & 15;
    int t = idx >> 13;
    xenc[t * NB + j * 16 + b] = x[(b * T_IN + t) * 512 + j];
}

// ---------------------------------------------------------------------------
// Hop GEMM: Y(512 x ncols) = M(512x512) @ X.  64x64 tile, 256 threads,
// 4x4 micro-tile, Kt=16, K=512, register-prefetch double buffering.
// ---------------------------------------------------------------------------
__global__ __launch_bounds__(256) void ghop_kernel(HopA a) {
    int z = blockIdx.z;
    const float* Wm = a.M[z];
    const float* X; float* Y; int rs, cs, ncols, col0;
    if (a.selfSrc) {
        X = Wm; rs = 512; cs = 1; ncols = 512; col0 = blockIdx.x * 64; Y = a.dst0[z];
    } else if ((int)blockIdx.x < a.tiles0) {
        X = a.src0; rs = a.rs0; cs = a.cs0; ncols = a.ncols0;
        col0 = blockIdx.x * 64; Y = a.dst0[z];
    } else {
        X = a.src1; rs = a.rs1; cs = a.cs1; ncols = a.ncols1;
        col0 = ((int)blockIdx.x - a.tiles0) * 64; Y = a.dst1[z];
    }

    int row0 = blockIdx.y * 64;
    int tid = threadIdx.x;
    int tx = tid & 15, ty = tid >> 4;
    int kkA = tid & 15, rrA = tid >> 4;
    int ccB = tid & 63, kkB = tid >> 6;

    __shared__ float As[16][68], Bs[16][68];
    float acc[4][4] = {};

    const float* wp = Wm + (row0 + rrA) * 512 + kkA;
    int cB = col0 + ccB;
    bool okB = cB < ncols;
    const float* xp = X + (size_t)cB * cs + (size_t)kkB * rs;

    float ra[4], rb[4];
#pragma unroll
    for (int p = 0; p < 4; ++p) ra[p] = wp[p * 16 * 512];
#pragma unroll
    for (int p = 0; p < 4; ++p) rb[p] = okB ? xp[(size_t)(p * 4) * rs] : 0.0f;

    for (int k0 = 0; k0 < 512; k0 += 16) {
#pragma unroll
        for (int p = 0; p < 4; ++p) As[kkA][rrA + p * 16] = ra[p];
#pragma unroll
        for (int p = 0; p < 4; ++p) Bs[kkB + p * 4][ccB] = rb[p];
        __syncthreads();
        if (k0 + 16 < 512) {
            int kn = k0 + 16;
#pragma unroll
            for (int p = 0; p < 4; ++p) ra[p] = wp[p * 16 * 512 + kn];
#pragma unroll
            for (int p = 0; p < 4; ++p) rb[p] = okB ? xp[(size_t)(kn + p * 4) * rs] : 0.0f;
        }
#pragma unroll
        for (int k = 0; k < 16; ++k) {
            const float4 a4 = *(const float4*)&As[k][ty * 4];
            const float4 b4 = *(const float4*)&Bs[k][tx * 4];
            float av[4] = { a4.x, a4.y, a4.z, a4.w };
            float bv[4] = { b4.x, b4.y, b4.z, b4.w };
#pragma unroll
            for (int i = 0; i < 4; ++i)
#pragma unroll
                for (int j = 0; j < 4; ++j)
                    acc[i][j] = fmaf(av[i], bv[j], acc[i][j]);
        }
        __syncthreads();
    }

    int colw = col0 + tx * 4;
    if (colw < ncols) {
#pragma unroll
        for (int i = 0; i < 4; ++i) {
            int row = row0 + ty * 4 + i;
            *(float4*)&Y[(size_t)row * ncols + colw] =
                make_float4(acc[i][0], acc[i][1], acc[i][2], acc[i][3]);
        }
    }
}

// ---------------------------------------------------------------------------
// Segmented-K lin core: 32-row x 64-col tile, 256 threads, 2x4 micro-tile,
// register-prefetch double buffering across the flattened (seg,k0) walk.
// ---------------------------------------------------------------------------
__device__ __forceinline__ void lin_tile(const Segs& segs, const float* __restrict__ W,
                                         int row0, int tid, float acc[2][4],
                                         float (*As)[34], float (*Ws)[68]) {
    int kkA = tid & 15, rrA = tid >> 4;
    int ccW = tid & 63, kkW = tid >> 6;
    int tx = tid & 15, ty = tid >> 4;

    int s = 0, k0 = 0;
    float a0, a1, w[4];
    auto load = [&](int s_, int k0_) {
        const float* p = segs.p[s_];
        int st = segs.stride[s_];
        int kt = segs.len[s_] - k0_; if (kt > 16) kt = 16;
        int wr = segs.wrow[s_] + k0_;
        a0 = (kkA < kt) ? p[(size_t)(row0 + rrA) * st + k0_ + kkA] : 0.0f;
        a1 = (kkA < kt) ? p[(size_t)(row0 + rrA + 16) * st + k0_ + kkA] : 0.0f;
#pragma unroll
        for (int q = 0; q < 4; ++q)
            w[q] = (kkW + q * 4 < kt) ? W[(size_t)(wr + kkW + q * 4) * 64 + ccW] : 0.0f;
    };
    load(0, 0);
    for (;;) {
        As[kkA][rrA] = a0;
        As[kkA][rrA + 16] = a1;
#pragma unroll
        for (int q = 0; q < 4; ++q) Ws[kkW + q * 4][ccW] = w[q];
        __syncthreads();
        int s2 = s, k2 = k0 + 16;
        bool more = true;
        if (k2 >= segs.len[s2]) { k2 = 0; ++s2; if (s2 >= segs.n) more = false; }
        if (more) load(s2, k2);
#pragma unroll
        for (int k = 0; k < 16; ++k) {
            const float2 a2 = *(const float2*)&As[k][ty * 2];
            const float4 b4 = *(const float4*)&Ws[k][tx * 4];
            float av[2] = { a2.x, a2.y };
            float bv[4] = { b4.x, b4.y, b4.z, b4.w };
#pragma unroll
            for (int i = 0; i < 2; ++i)
#pragma unroll
                for (int j = 0; j < 4; ++j)
                    acc[i][j] = fmaf(av[i], bv[j], acc[i][j]);
        }
        __syncthreads();
        if (!more) break;
        s = s2; k0 = k2;
    }
}

__device__ __forceinline__ float sigmoid_fast(float x) {
    return 1.0f / (1.0f + __expf(-x));
}
__device__ __forceinline__ float tanh_fast(float x) {
    float e = __expf(2.0f * x);
    return 1.0f - 2.0f / (e + 1.0f);
}

// r/z gates: grid (256, 2). y==0: G = sigmoid(pre_r)*h ; y==1: Z = sigmoid(pre_z)
__global__ __launch_bounds__(256) void lin_rz_kernel(
    Segs segs, const float* __restrict__ Wr, const float* __restrict__ br,
    const float* __restrict__ Wz, const float* __restrict__ bz,
    const float* __restrict__ h, float* __restrict__ G, float* __restrict__ Z) {
    __shared__ float As[16][34], Ws[16][68];
    int row0 = blockIdx.x * 32;
    int tid = threadIdx.x;
    const float* W = blockIdx.y ? Wz : Wr;
    const float* bias = blockIdx.y ? bz : br;
    float acc[2][4] = {};
    lin_tile(segs, W, row0, tid, acc, As, Ws);
    int tx = tid & 15, ty = tid >> 4;
    int colw = tx * 4;
#pragma unroll
    for (int i = 0; i < 2; ++i) {
        int row = row0 + ty * 2 + i;
        size_t base = (size_t)row * 64 + colw;
        float4 o;
        if (blockIdx.y == 0) {
            float4 hv = *(const float4*)&h[base];
            o.x = sigmoid_fast(acc[i][0] + bias[colw + 0]) * hv.x;
            o.y = sigmoid_fast(acc[i][1] + bias[colw + 1]) * hv.y;
            o.z = sigmoid_fast(acc[i][2] + bias[colw + 2]) * hv.z;
            o.w = sigmoid_fast(acc[i][3] + bias[colw + 3]) * hv.w;
            *(float4*)&G[base] = o;
        } else {
            o.x = sigmoid_fast(acc[i][0] + bias[colw + 0]);
            o.y = sigmoid_fast(acc[i][1] + bias[colw + 1]);
            o.z = sigmoid_fast(acc[i][2] + bias[colw + 2]);
            o.w = sigmoid_fast(acc[i][3] + bias[colw + 3]);
            *(float4*)&Z[base] = o;
        }
    }
}

// n gate + GRU update (in place on h); optional fused decoder projection.
__global__ __launch_bounds__(256) void lin_n_kernel(
    Segs segs, const float* __restrict__ Wn, const float* __restrict__ bn,
    const float* __restrict__ Zb, float* __restrict__ h, int doProj,
    const float* __restrict__ Wp, const float* __restrict__ bp,
    float* __restrict__ out, float* __restrict__ di, int t) {
    __shared__ float As[16][34], Ws[16][68];
    int row0 = blockIdx.x * 32;
    int tid = threadIdx.x;
    float acc[2][4] = {};
    lin_tile(segs, Wn, row0, tid, acc, As, Ws);
    int tx = tid & 15, ty = tid >> 4;
    int colw = tx * 4;
    float hnew[2][4];
#pragma unroll
    for (int i = 0; i < 2; ++i) {
        int row = row0 + ty * 2 + i;
        size_t base = (size_t)row * 64 + colw;
        float4 hv = *(const float4*)&h[base];
        float4 zv = *(const float4*)&Zb[base];
        float4 o;
        o.x = (1.0f - zv.x) * hv.x + zv.x * tanh_fast(acc[i][0] + bn[colw + 0]);
        o.y = (1.0f - zv.y) * hv.y + zv.y * tanh_fast(acc[i][1] + bn[colw + 1]);
        o.z = (1.0f - zv.z) * hv.z + zv.z * tanh_fast(acc[i][2] + bn[colw + 2]);
        o.w = (1.0f - zv.w) * hv.w + zv.w * tanh_fast(acc[i][3] + bn[colw + 3]);
        *(float4*)&h[base] = o;
        hnew[i][0] = o.x; hnew[i][1] = o.y; hnew[i][2] = o.z; hnew[i][3] = o.w;
    }
    if (doProj) {
        float p0 = 0.0f, p1 = 0.0f;
#pragma unroll
        for (int j = 0; j < 4; ++j) {
            float wv = Wp[colw + j];
            p0 = fmaf(hnew[0][j], wv, p0);
            p1 = fmaf(hnew[1][j], wv, p1);
        }
        for (int m = 1; m < 16; m <<= 1) {
            p0 += __shfl_xor(p0, m, 64);
            p1 += __shfl_xor(p1, m, 64);
        }
        if (tx == 0) {
            float bpv = bp[0];
            int r0 = row0 + ty * 2;
#pragma unroll
            for (int i = 0; i < 2; ++i) {
                int row = r0 + i;
                float y = (i ? p1 : p0) + bpv;
                int n = row >> 4, b = row & 15;
                out[(b * T_OUT + t) * 512 + n] = y;
                di[row] = y;
            }
        }
    }
}

// ---------------------------------------------------------------------------
extern "C" void kernel_launch(void* const* d_in, const int* in_sizes, int n_in,
                              void* d_out, int out_size, void* d_ws, size_t ws_size,
                              hipStream_t stream) {
    (void)in_sizes; (void)n_in; (void)out_size; (void)ws_size;
    const float* x   = (const float*)d_in[0];
    const float* A   = (const float*)d_in[1];
    const float* Wr0 = (const float*)d_in[2];  const float* br0 = (const float*)d_in[3];
    const float* Wz0 = (const float*)d_in[4];  const float* bz0 = (const float*)d_in[5];
    const float* Wn0 = (const float*)d_in[6];  const float* bn0 = (const float*)d_in[7];
    const float* Wr1 = (const float*)d_in[8];  const float* br1 = (const float*)d_in[9];
    const float* Wz1 = (const float*)d_in[10]; const float* bz1 = (const float*)d_in[11];
    const float* Wn1 = (const float*)d_in[12]; const float* bn1 = (const float*)d_in[13];
    const float* Wp  = (const float*)d_in[14]; const float* bp  = (const float*)d_in[15];
    float* out = (float*)d_out;

    float* ws = (float*)d_ws;
    size_t off = 0;
    auto alloc = [&](size_t nf) { float* p = ws + off; off += nf; return p; };
    float* Wf  = alloc(262144); float* Wb  = alloc(262144);
    float* W2f = alloc(262144); float* W2b = alloc(262144);
    float* rs  = alloc(512);    float* cs  = alloc(512);
    float* xenc = alloc((size_t)T_IN * NB);
    float* HA[4]; float* HB[4]; float* HG[4]; float* HXS[4];
    for (int m = 0; m < 4; ++m) HA[m]  = alloc(524288);
    for (int m = 0; m < 4; ++m) HB[m]  = alloc(524288);
    for (int m = 0; m < 4; ++m) HG[m]  = alloc(524288);
    for (int m = 0; m < 4; ++m) HXS[m] = alloc(8192);
    float* G  = alloc(524288);
    float* Zb = alloc(524288);
    float* h0 = alloc(524288);
    float* h1 = alloc(524288);
    float* di = alloc(8192);

    hipMemsetAsync(h0, 0, 524288 * sizeof(float), stream);
    hipMemsetAsync(h1, 0, 524288 * sizeof(float), stream);

    xenc_kernel<<<dim3((T_IN * NB) / 256), 256, 0, stream>>>(x, xenc);
    sums_kernel<<<dim3(512), 256, 0, stream>>>(A, rs, cs);
    fill_kernel<<<dim3(512), 256, 0, stream>>>(A, rs, cs, Wf, Wb);

    { // W2f = Wf@Wf, W2b = Wb@Wb
        HopA w2 = {};
        w2.M[0] = Wf; w2.M[1] = Wb; w2.M[2] = Wf; w2.M[3] = Wf;
        w2.dst0[0] = W2f; w2.dst0[1] = W2b;
        w2.selfSrc = 1;
        ghop_kernel<<<dim3(8, 8, 2), 256, 0, stream>>>(w2);
    }

    auto cell0 = [&](const float* xcur) {
        HopA a = {};
        a.M[0] = Wf; a.M[1] = W2f; a.M[2] = Wb; a.M[3] = W2b;
        a.src0 = h0; a.rs0 = 1024; a.cs0 = 1; a.ncols0 = 1024; a.tiles0 = 16;
        a.src1 = xcur; a.rs1 = 16; a.cs1 = 1; a.ncols1 = 16;
        for (int m = 0; m < 4; ++m) { a.dst0[m] = HB[m]; a.dst1[m] = HXS[m]; }
        ghop_kernel<<<dim3(17, 8, 4), 256, 0, stream>>>(a);

        Segs srz; srz.n = 10;
        srz.p[0] = xcur; srz.stride[0] = 1;  srz.len[0] = 1;  srz.wrow[0] = 0;
        srz.p[1] = h0;   srz.stride[1] = 64; srz.len[1] = 64; srz.wrow[1] = 1;
        for (int m = 0; m < 4; ++m) {
            srz.p[2 + 2 * m] = HXS[m]; srz.stride[2 + 2 * m] = 1;  srz.len[2 + 2 * m] = 1;
            srz.wrow[2 + 2 * m] = 65 * (m + 1);
            srz.p[3 + 2 * m] = HB[m];  srz.stride[3 + 2 * m] = 64; srz.len[3 + 2 * m] = 64;
            srz.wrow[3 + 2 * m] = 65 * (m + 1) + 1;
        }
        lin_rz_kernel<<<dim3(256, 2), 256, 0, stream>>>(srz, Wr0, br0, Wz0, bz0, h0, G, Zb);

        HopA ag = {};
        ag.M[0] = Wf; ag.M[1] = W2f; ag.M[2] = Wb; ag.M[3] = W2b;
        ag.src0 = G; ag.rs0 = 1024; ag.cs0 = 1; ag.ncols0 = 1024; ag.tiles0 = 16;
        for (int m = 0; m < 4; ++m) ag.dst0[m] = HG[m];
        ghop_kernel<<<dim3(16, 8, 4), 256, 0, stream>>>(ag);

        Segs sn; sn.n = 10;
        sn.p[0] = xcur; sn.stride[0] = 1;  sn.len[0] = 1;  sn.wrow[0] = 0;
        sn.p[1] = G;    sn.stride[1] = 64; sn.len[1] = 64; sn.wrow[1] = 1;
        for (int m = 0; m < 4; ++m) {
            sn.p[2 + 2 * m] = HXS[m]; sn.stride[2 + 2 * m] = 1;  sn.len[2 + 2 * m] = 1;
            sn.wrow[2 + 2 * m] = 65 * (m + 1);
            sn.p[3 + 2 * m] = HG[m];  sn.stride[3 + 2 * m] = 64; sn.len[3 + 2 * m] = 64;
            sn.wrow[3 + 2 * m] = 65 * (m + 1) + 1;
        }
        lin_n_kernel<<<dim3(256), 256, 0, stream>>>(sn, Wn0, bn0, Zb, h0, 0,
                                                    (const float*)nullptr, (const float*)nullptr,
                                                    (float*)nullptr, (float*)nullptr, 0);
    };

    auto cell1 = [&](int doProj, int t) {
        HopA a = {};
        a.M[0] = Wf; a.M[1] = W2f; a.M[2] = Wb; a.M[3] = W2b;
        a.src0 = h0; a.rs0 = 1024; a.cs0 = 1; a.ncols0 = 1024; a.tiles0 = 16;
        a.src1 = h1; a.rs1 = 1024; a.cs1 = 1; a.ncols1 = 1024;
        for (int m = 0; m < 4; ++m) { a.dst0[m] = HA[m]; a.dst1[m] = HB[m]; }
        ghop_kernel<<<dim3(32, 8, 4), 256, 0, stream>>>(a);

        Segs srz; srz.n = 10;
        srz.p[0] = h0; srz.stride[0] = 64; srz.len[0] = 64; srz.wrow[0] = 0;
        srz.p[1] = h1; srz.stride[1] = 64; srz.len[1] = 64; srz.wrow[1] = 64;
        for (int m = 0; m < 4; ++m) {
            srz.p[2 + 2 * m] = HA[m]; srz.stride[2 + 2 * m] = 64; srz.len[2 + 2 * m] = 64;
            srz.wrow[2 + 2 * m] = 128 * (m + 1);
            srz.p[3 + 2 * m] = HB[m]; srz.stride[3 + 2 * m] = 64; srz.len[3 + 2 * m] = 64;
            srz.wrow[3 + 2 * m] = 128 * (m + 1) + 64;
        }
        lin_rz_kernel<<<dim3(256, 2), 256, 0, stream>>>(srz, Wr1, br1, Wz1, bz1, h1, G, Zb);

        HopA ag = {};
        ag.M[0] = Wf; ag.M[1] = W2f; ag.M[2] = Wb; ag.M[3] = W2b;
        ag.src0 = G; ag.rs0 = 1024; ag.cs0 = 1; ag.ncols0 = 1024; ag.tiles0 = 16;
        for (int m = 0; m < 4; ++m) ag.dst0[m] = HG[m];
        ghop_kernel<<<dim3(16, 8, 4), 256, 0, stream>>>(ag);

        Segs sn; sn.n = 10;
        sn.p[0] = h0; sn.stride[0] = 64; sn.len[0] = 64; sn.wrow[0] = 0;
        sn.p[1] = G;  sn.stride[1] = 64; sn.len[1] = 64; sn.wrow[1] = 64;
        for (int m = 0; m < 4; ++m) {
            sn.p[2 + 2 * m] = HA[m]; sn.stride[2 + 2 * m] = 64; sn.len[2 + 2 * m] = 64;
            sn.wrow[2 + 2 * m] = 128 * (m + 1);
            sn.p[3 + 2 * m] = HG[m]; sn.stride[3 + 2 * m] = 64; sn.len[3 + 2 * m] = 64;
            sn.wrow[3 + 2 * m] = 128 * (m + 1) + 64;
        }
        lin_n_kernel<<<dim3(256), 256, 0, stream>>>(sn, Wn1, bn1, Zb, h1, doProj,
                                                    Wp, bp, out, di, t);
    };

    for (int t = 0; t < T_IN; ++t) {
        cell0(xenc + (size_t)t * NB);
        cell1(0, 0);
    }
    for (int t = 0; t < T_OUT; ++t) {
        const float* xcur = (t == 0) ? (xenc + (size_t)(T_IN - 1) * NB) : di;
        cell0(xcur);
        cell1(1, t);
    }
}

// Round 3
// 6270.003 us; speedup vs baseline: 2.5211x; 1.1765x over previous
//
#include <hip/hip_runtime.h>
#include <math.h>

#define T_IN   12
#define T_OUT  12
#define NB     8192          /* 512 nodes x 16 batch, row id = n*16+b */
#define EPSV   1e-6f

typedef __attribute__((ext_vector_type(8))) short short8;
typedef __attribute__((ext_vector_type(4))) float floatx4;

// ---------------------------------------------------------------------------
// bf16 split helpers (RNE)
// ---------------------------------------------------------------------------
__device__ __forceinline__ unsigned short f2bf(float x) {
    union { float f; unsigned u; } v; v.f = x;
    unsigned r = v.u + 0x7fffu + ((v.u >> 16) & 1u);
    return (unsigned short)(r >> 16);
}
__device__ __forceinline__ float bf2f(unsigned short h) {
    union { float f; unsigned u; } v; v.u = ((unsigned)h) << 16;
    return v.f;
}

// ---------------------------------------------------------------------------
// Segmented-K descriptor for the linear (dconv concat @ W) GEMMs.
// ---------------------------------------------------------------------------
struct Segs { const float* p[10]; int stride[10]; int len[10]; int wrow[10]; int n; };

// fp32 hop GEMM job (setup-only: W^2 build)
struct HopA {
    const float* M[4];
    const float* src0; const float* src1;
    float* dst0[4]; float* dst1[4];
    int rs0, cs0, ncols0, tiles0;
    int rs1, cs1, ncols1;
    int selfSrc;
};

// MFMA hop job: Y[z] = M[z] @ X, A operands pre-packed bf16 hi/lo
struct HopM {
    const unsigned short* Ahi[4]; const unsigned short* Alo[4];
    const float* src0; const float* src1;
    float* dst0[4]; float* dst1[4];
    int ncols0, tiles0, ncols1;
};

struct XHop { const float* M[4]; float* dst[4]; };

struct WPack { const float* w[4]; unsigned short* hi[4]; unsigned short* lo[4]; };

// ---------------------------------------------------------------------------
// Random-walk normalization
// ---------------------------------------------------------------------------
__global__ void sums_kernel(const float* __restrict__ A, float* __restrict__ rs,
                            float* __restrict__ cs) {
    int i = blockIdx.x;
    int t = threadIdx.x;
    __shared__ float s1[256], s2[256];
    float a = A[i * 512 + t] + A[i * 512 + t + 256];
    float b = A[t * 512 + i] + A[(t + 256) * 512 + i];
    s1[t] = a; s2[t] = b;
    __syncthreads();
    for (int off = 128; off > 0; off >>= 1) {
        if (t < off) { s1[t] += s1[t + off]; s2[t] += s2[t + off]; }
        __syncthreads();
    }
    if (t == 0) { rs[i] = s1[0]; cs[i] = s2[0]; }
}

__global__ void fill_kernel(const float* __restrict__ A, const float* __restrict__ rs,
                            const float* __restrict__ cs, float* __restrict__ Wf,
                            float* __restrict__ Wb) {
    int i = blockIdx.x;
    float irs = 1.0f / (rs[i] + EPSV);
    float ics = 1.0f / (cs[i] + EPSV);
    for (int j = threadIdx.x; j < 512; j += 256) {
        Wf[i * 512 + j] = A[i * 512 + j] * irs;
        Wb[i * 512 + j] = A[j * 512 + i] * ics;
    }
}

// Pre-transpose all encoder x slices: xenc[t][j*16+b] = x[b, t, j]
__global__ void xenc_kernel(const float* __restrict__ x, float* __restrict__ xenc) {
    int idx = blockIdx.x * 256 + threadIdx.x;
    if (idx >= T_IN * NB) return;
    int j = idx & 511;
    int b = (idx >> 9) & 15;
    int t = idx >> 13;
    xenc[t * NB + j * 16 + b] = x[(b * T_IN + t) * 512 + j];
}

// Pack W (512x512 fp32) into fragment-contiguous bf16 hi/lo:
// packed idx = ((m>>4)*64 + (k>>3))*128 + (m&15)*8 + (k&7)
__global__ void wpack_kernel(WPack a) {
    int z = blockIdx.y;
    int idx = blockIdx.x * 256 + threadIdx.x;   // 0..262143
    int m = idx >> 9, k = idx & 511;
    float x = a.w[z][idx];
    unsigned short h = f2bf(x);
    unsigned short l = f2bf(x - bf2f(h));
    int p = (((m >> 4) * 64 + (k >> 3)) * 16 + (m & 15)) * 8 + (k & 7);
    a.hi[z][p] = h;
    a.lo[z][p] = l;
}

// ---------------------------------------------------------------------------
// fp32 hop GEMM (setup-only, builds W^2). 64x64 tile, 4x4 micro.
// ---------------------------------------------------------------------------
__global__ __launch_bounds__(256) void ghop_kernel(HopA a) {
    int z = blockIdx.z;
    const float* Wm = a.M[z];
    const float* X; float* Y; int rs, cs, ncols, col0;
    if (a.selfSrc) {
        X = Wm; rs = 512; cs = 1; ncols = 512; col0 = blockIdx.x * 64; Y = a.dst0[z];
    } else if ((int)blockIdx.x < a.tiles0) {
        X = a.src0; rs = a.rs0; cs = a.cs0; ncols = a.ncols0;
        col0 = blockIdx.x * 64; Y = a.dst0[z];
    } else {
        X = a.src1; rs = a.rs1; cs = a.cs1; ncols = a.ncols1;
        col0 = ((int)blockIdx.x - a.tiles0) * 64; Y = a.dst1[z];
    }

    int row0 = blockIdx.y * 64;
    int tid = threadIdx.x;
    int tx = tid & 15, ty = tid >> 4;
    int kkA = tid & 15, rrA = tid >> 4;
    int ccB = tid & 63, kkB = tid >> 6;

    __shared__ float As[16][68], Bs[16][68];
    float acc[4][4] = {};

    const float* wp = Wm + (row0 + rrA) * 512 + kkA;
    int cB = col0 + ccB;
    bool okB = cB < ncols;
    const float* xp = X + (size_t)cB * cs + (size_t)kkB * rs;

    float ra[4], rb[4];
#pragma unroll
    for (int p = 0; p < 4; ++p) ra[p] = wp[p * 16 * 512];
#pragma unroll
    for (int p = 0; p < 4; ++p) rb[p] = okB ? xp[(size_t)(p * 4) * rs] : 0.0f;

    for (int k0 = 0; k0 < 512; k0 += 16) {
#pragma unroll
        for (int p = 0; p < 4; ++p) As[kkA][rrA + p * 16] = ra[p];
#pragma unroll
        for (int p = 0; p < 4; ++p) Bs[kkB + p * 4][ccB] = rb[p];
        __syncthreads();
        if (k0 + 16 < 512) {
            int kn = k0 + 16;
#pragma unroll
            for (int p = 0; p < 4; ++p) ra[p] = wp[p * 16 * 512 + kn];
#pragma unroll
            for (int p = 0; p < 4; ++p) rb[p] = okB ? xp[(size_t)(kn + p * 4) * rs] : 0.0f;
        }
#pragma unroll
        for (int k = 0; k < 16; ++k) {
            const float4 a4 = *(const float4*)&As[k][ty * 4];
            const float4 b4 = *(const float4*)&Bs[k][tx * 4];
            float av[4] = { a4.x, a4.y, a4.z, a4.w };
            float bv[4] = { b4.x, b4.y, b4.z, b4.w };
#pragma unroll
            for (int i = 0; i < 4; ++i)
#pragma unroll
                for (int j = 0; j < 4; ++j)
                    acc[i][j] = fmaf(av[i], bv[j], acc[i][j]);
        }
        __syncthreads();
    }

    int colw = col0 + tx * 4;
    if (colw < ncols) {
#pragma unroll
        for (int i = 0; i < 4; ++i) {
            int row = row0 + ty * 4 + i;
            *(float4*)&Y[(size_t)row * ncols + colw] =
                make_float4(acc[i][0], acc[i][1], acc[i][2], acc[i][3]);
        }
    }
}

// ---------------------------------------------------------------------------
// MFMA hop GEMM: Y[z](512 x ncols) = M[z](512x512) @ X(512 x ncols), fp32 in/out,
// split-bf16 3-pass internally. Block tile 128m x 64n x 32k, 4 waves,
// wave tile 64m x 32n (4x2 frags of 16x16x32).
// ---------------------------------------------------------------------------
__global__ __launch_bounds__(256) void ghop_mfma(HopM a) {
    int z = blockIdx.z;
    int nt = blockIdx.x;
    const float* X; float* Y; int ncols, c0;
    if (nt < a.tiles0) { X = a.src0; Y = a.dst0[z]; ncols = a.ncols0; c0 = nt * 64; }
    else { X = a.src1; Y = a.dst1[z]; ncols = a.ncols1; c0 = (nt - a.tiles0) * 64; }
    const unsigned short* Ahi = a.Ahi[z];
    const unsigned short* Alo = a.Alo[z];
    int bm = blockIdx.y * 128;

    __shared__ unsigned short Bhi_s[64][40];
    __shared__ unsigned short Blo_s[64][40];

    int tid = threadIdx.x;
    int lane = tid & 63;
    int w = tid >> 6;
    int wm = (w & 1) * 64;          // wave m-offset within block
    int wn = (w >> 1) * 32;         // wave n-offset within block
    int ln = lane & 15;
    int quad = lane >> 4;

    // staging: thread covers col sc (0..63), k-oct skh (0..3): k = skh*8+j
    int sc = tid & 63;
    int skh = tid >> 6;

    floatx4 acc[4][2];
#pragma unroll
    for (int mi = 0; mi < 4; ++mi)
#pragma unroll
        for (int ci = 0; ci < 2; ++ci) acc[mi][ci] = (floatx4)0.0f;

    const float* xbase = X + (size_t)(c0 + sc);
    // A-frag base byte offsets: element = ((mt*64 + ko)*16 + ln)*8, mt = (bm+wm)/16+mi
    int mtb = (bm + wm) >> 4;

    float xv[8];
#pragma unroll
    for (int j = 0; j < 8; ++j)
        xv[j] = xbase[(size_t)(skh * 8 + j) * ncols];

    for (int k0 = 0; k0 < 512; k0 += 32) {
        short8 h8, l8;
#pragma unroll
        for (int j = 0; j < 8; ++j) {
            unsigned short h = f2bf(xv[j]);
            h8[j] = (short)h;
            l8[j] = (short)f2bf(xv[j] - bf2f(h));
        }
        __syncthreads();
        *(short8*)&Bhi_s[sc][skh * 8] = h8;
        *(short8*)&Blo_s[sc][skh * 8] = l8;
        __syncthreads();
        if (k0 + 32 < 512) {
            int kn = k0 + 32;
#pragma unroll
            for (int j = 0; j < 8; ++j)
                xv[j] = xbase[(size_t)(kn + skh * 8 + j) * ncols];
        }
        short8 bh[2], bl[2];
#pragma unroll
        for (int ci = 0; ci < 2; ++ci) {
            bh[ci] = *(const short8*)&Bhi_s[wn + ci * 16 + ln][quad * 8];
            bl[ci] = *(const short8*)&Blo_s[wn + ci * 16 + ln][quad * 8];
        }
        int kob = (k0 >> 3) + quad;
#pragma unroll
        for (int mi = 0; mi < 4; ++mi) {
            size_t aoff = ((size_t)((mtb + mi) * 64 + kob) * 16 + ln) * 8;
            short8 Ah = *(const short8*)(Ahi + aoff);
            short8 Al = *(const short8*)(Alo + aoff);
#pragma unroll
            for (int ci = 0; ci < 2; ++ci) {
                acc[mi][ci] = __builtin_amdgcn_mfma_f32_16x16x32_bf16(Ah, bh[ci], acc[mi][ci], 0, 0, 0);
                acc[mi][ci] = __builtin_amdgcn_mfma_f32_16x16x32_bf16(Ah, bl[ci], acc[mi][ci], 0, 0, 0);
                acc[mi][ci] = __builtin_amdgcn_mfma_f32_16x16x32_bf16(Al, bh[ci], acc[mi][ci], 0, 0, 0);
            }
        }
    }

    // epilogue: D[row = quad*4+r][col = ln] per frag
#pragma unroll
    for (int mi = 0; mi < 4; ++mi) {
#pragma unroll
        for (int ci = 0; ci < 2; ++ci) {
            int mrow = bm + wm + mi * 16 + quad * 4;
            int col = c0 + wn + ci * 16 + ln;
#pragma unroll
            for (int r = 0; r < 4; ++r)
                Y[(size_t)(mrow + r) * ncols + col] = acc[mi][ci][r];
        }
    }
}

// ---------------------------------------------------------------------------
// Tiny x-hop (fp32): dst[z][m*16+c] = sum_k M[z][m][k] * xv[k*16+c]   (c = batch)
// ---------------------------------------------------------------------------
__global__ void xhop_kernel(XHop a, const float* __restrict__ xv) {
    int z = blockIdx.y;
    const float* M = a.M[z];
    int m = blockIdx.x * 16 + (threadIdx.x >> 4);
    int c = threadIdx.x & 15;
    const float* wrow = M + (size_t)m * 512;
    float s = 0.0f;
#pragma unroll 4
    for (int k = 0; k < 512; ++k)
        s = fmaf(wrow[k], xv[k * 16 + c], s);
    a.dst[z][m * 16 + c] = s;
}

// ---------------------------------------------------------------------------
// Segmented-K lin core (fp32 VALU): 32-row x 64-col tile, 2x4 micro.
// ---------------------------------------------------------------------------
__device__ __forceinline__ void lin_tile(const Segs& segs, const float* __restrict__ W,
                                         int row0, int tid, float acc[2][4],
                                         float (*As)[34], float (*Ws)[68]) {
    int kkA = tid & 15, rrA = tid >> 4;
    int ccW = tid & 63, kkW = tid >> 6;
    int tx = tid & 15, ty = tid >> 4;

    int s = 0, k0 = 0;
    float a0, a1, w[4];
    auto load = [&](int s_, int k0_) {
        const float* p = segs.p[s_];
        int st = segs.stride[s_];
        int kt = segs.len[s_] - k0_; if (kt > 16) kt = 16;
        int wr = segs.wrow[s_] + k0_;
        a0 = (kkA < kt) ? p[(size_t)(row0 + rrA) * st + k0_ + kkA] : 0.0f;
        a1 = (kkA < kt) ? p[(size_t)(row0 + rrA + 16) * st + k0_ + kkA] : 0.0f;
#pragma unroll
        for (int q = 0; q < 4; ++q)
            w[q] = (kkW + q * 4 < kt) ? W[(size_t)(wr + kkW + q * 4) * 64 + ccW] : 0.0f;
    };
    load(0, 0);
    for (;;) {
        As[kkA][rrA] = a0;
        As[kkA][rrA + 16] = a1;
#pragma unroll
        for (int q = 0; q < 4; ++q) Ws[kkW + q * 4][ccW] = w[q];
        __syncthreads();
        int s2 = s, k2 = k0 + 16;
        bool more = true;
        if (k2 >= segs.len[s2]) { k2 = 0; ++s2; if (s2 >= segs.n) more = false; }
        if (more) load(s2, k2);
#pragma unroll
        for (int k = 0; k < 16; ++k) {
            const float2 a2 = *(const float2*)&As[k][ty * 2];
            const float4 b4 = *(const float4*)&Ws[k][tx * 4];
            float av[2] = { a2.x, a2.y };
            float bv[4] = { b4.x, b4.y, b4.z, b4.w };
#pragma unroll
            for (int i = 0; i < 2; ++i)
#pragma unroll
                for (int j = 0; j < 4; ++j)
                    acc[i][j] = fmaf(av[i], bv[j], acc[i][j]);
        }
        __syncthreads();
        if (!more) break;
        s = s2; k0 = k2;
    }
}

__device__ __forceinline__ float sigmoid_fast(float x) {
    return 1.0f / (1.0f + __expf(-x));
}
__device__ __forceinline__ float tanh_fast(float x) {
    float e = __expf(2.0f * x);
    return 1.0f - 2.0f / (e + 1.0f);
}

// r/z gates: grid (256, 2). y==0: G = sigmoid(pre_r)*h ; y==1: Z = sigmoid(pre_z)
__global__ __launch_bounds__(256) void lin_rz_kernel(
    Segs segs, const float* __restrict__ Wr, const float* __restrict__ br,
    const float* __restrict__ Wz, const float* __restrict__ bz,
    const float* __restrict__ h, float* __restrict__ G, float* __restrict__ Z) {
    __shared__ float As[16][34], Ws[16][68];
    int row0 = blockIdx.x * 32;
    int tid = threadIdx.x;
    const float* W = blockIdx.y ? Wz : Wr;
    const float* bias = blockIdx.y ? bz : br;
    float acc[2][4] = {};
    lin_tile(segs, W, row0, tid, acc, As, Ws);
    int tx = tid & 15, ty = tid >> 4;
    int colw = tx * 4;
#pragma unroll
    for (int i = 0; i < 2; ++i) {
        int row = row0 + ty * 2 + i;
        size_t base = (size_t)row * 64 + colw;
        float4 o;
        if (blockIdx.y == 0) {
            float4 hv = *(const float4*)&h[base];
            o.x = sigmoid_fast(acc[i][0] + bias[colw + 0]) * hv.x;
            o.y = sigmoid_fast(acc[i][1] + bias[colw + 1]) * hv.y;
            o.z = sigmoid_fast(acc[i][2] + bias[colw + 2]) * hv.z;
            o.w = sigmoid_fast(acc[i][3] + bias[colw + 3]) * hv.w;
            *(float4*)&G[base] = o;
        } else {
            o.x = sigmoid_fast(acc[i][0] + bias[colw + 0]);
            o.y = sigmoid_fast(acc[i][1] + bias[colw + 1]);
            o.z = sigmoid_fast(acc[i][2] + bias[colw + 2]);
            o.w = sigmoid_fast(acc[i][3] + bias[colw + 3]);
            *(float4*)&Z[base] = o;
        }
    }
}

// n gate + GRU update (in place on h); optional fused decoder projection.
__global__ __launch_bounds__(256) void lin_n_kernel(
    Segs segs, const float* __restrict__ Wn, const float* __restrict__ bn,
    const float* __restrict__ Zb, float* __restrict__ h, int doProj,
    const float* __restrict__ Wp, const float* __restrict__ bp,
    float* __restrict__ out, float* __restrict__ di, int t) {
    __shared__ float As[16][34], Ws[16][68];
    int row0 = blockIdx.x * 32;
    int tid = threadIdx.x;
    float acc[2][4] = {};
    lin_tile(segs, Wn, row0, tid, acc, As, Ws);
    int tx = tid & 15, ty = tid >> 4;
    int colw = tx * 4;
    float hnew[2][4];
#pragma unroll
    for (int i = 0; i < 2; ++i) {
        int row = row0 + ty * 2 + i;
        size_t base = (size_t)row * 64 + colw;
        float4 hv = *(const float4*)&h[base];
        float4 zv = *(const float4*)&Zb[base];
        float4 o;
        o.x = (1.0f - zv.x) * hv.x + zv.x * tanh_fast(acc[i][0] + bn[colw + 0]);
        o.y = (1.0f - zv.y) * hv.y + zv.y * tanh_fast(acc[i][1] + bn[colw + 1]);
        o.z = (1.0f - zv.z) * hv.z + zv.z * tanh_fast(acc[i][2] + bn[colw + 2]);
        o.w = (1.0f - zv.w) * hv.w + zv.w * tanh_fast(acc[i][3] + bn[colw + 3]);
        *(float4*)&h[base] = o;
        hnew[i][0] = o.x; hnew[i][1] = o.y; hnew[i][2] = o.z; hnew[i][3] = o.w;
    }
    if (doProj) {
        float p0 = 0.0f, p1 = 0.0f;
#pragma unroll
        for (int j = 0; j < 4; ++j) {
            float wv = Wp[colw + j];
            p0 = fmaf(hnew[0][j], wv, p0);
            p1 = fmaf(hnew[1][j], wv, p1);
        }
        for (int m = 1; m < 16; m <<= 1) {
            p0 += __shfl_xor(p0, m, 64);
            p1 += __shfl_xor(p1, m, 64);
        }
        if (tx == 0) {
            float bpv = bp[0];
            int r0 = row0 + ty * 2;
#pragma unroll
            for (int i = 0; i < 2; ++i) {
                int row = r0 + i;
                float y = (i ? p1 : p0) + bpv;
                int n = row >> 4, b = row & 15;
                out[(b * T_OUT + t) * 512 + n] = y;
                di[row] = y;
            }
        }
    }
}

// ---------------------------------------------------------------------------
extern "C" void kernel_launch(void* const* d_in, const int* in_sizes, int n_in,
                              void* d_out, int out_size, void* d_ws, size_t ws_size,
                              hipStream_t stream) {
    (void)in_sizes; (void)n_in; (void)out_size; (void)ws_size;
    const float* x   = (const float*)d_in[0];
    const float* A   = (const float*)d_in[1];
    const float* Wr0 = (const float*)d_in[2];  const float* br0 = (const float*)d_in[3];
    const float* Wz0 = (const float*)d_in[4];  const float* bz0 = (const float*)d_in[5];
    const float* Wn0 = (const float*)d_in[6];  const float* bn0 = (const float*)d_in[7];
    const float* Wr1 = (const float*)d_in[8];  const float* br1 = (const float*)d_in[9];
    const float* Wz1 = (const float*)d_in[10]; const float* bz1 = (const float*)d_in[11];
    const float* Wn1 = (const float*)d_in[12]; const float* bn1 = (const float*)d_in[13];
    const float* Wp  = (const float*)d_in[14]; const float* bp  = (const float*)d_in[15];
    float* out = (float*)d_out;

    float* ws = (float*)d_ws;
    size_t off = 0;
    auto alloc = [&](size_t nf) { float* p = ws + off; off += nf; return p; };
    float* Wf  = alloc(262144); float* Wb  = alloc(262144);
    float* W2f = alloc(262144); float* W2b = alloc(262144);
    float* rs  = alloc(512);    float* cs  = alloc(512);
    float* xenc = alloc((size_t)T_IN * NB);
    float* HA[4]; float* HB[4]; float* HG[4]; float* HXS[4];
    for (int m = 0; m < 4; ++m) HA[m]  = alloc(524288);
    for (int m = 0; m < 4; ++m) HB[m]  = alloc(524288);
    for (int m = 0; m < 4; ++m) HG[m]  = alloc(524288);
    for (int m = 0; m < 4; ++m) HXS[m] = alloc(8192);
    float* G  = alloc(524288);
    float* Zb = alloc(524288);
    float* h0 = alloc(524288);
    float* h1 = alloc(524288);
    float* di = alloc(8192);
    // packed bf16 hi/lo W operands: 4 mats x 262144 ushorts each
    unsigned short* Whi[4]; unsigned short* Wlo[4];
    for (int m = 0; m < 4; ++m) Whi[m] = (unsigned short*)alloc(131072);
    for (int m = 0; m < 4; ++m) Wlo[m] = (unsigned short*)alloc(131072);

    hipMemsetAsync(h0, 0, 524288 * sizeof(float), stream);
    hipMemsetAsync(h1, 0, 524288 * sizeof(float), stream);

    xenc_kernel<<<dim3((T_IN * NB) / 256), 256, 0, stream>>>(x, xenc);
    sums_kernel<<<dim3(512), 256, 0, stream>>>(A, rs, cs);
    fill_kernel<<<dim3(512), 256, 0, stream>>>(A, rs, cs, Wf, Wb);

    { // W2f = Wf@Wf, W2b = Wb@Wb (fp32, setup only)
        HopA w2 = {};
        w2.M[0] = Wf; w2.M[1] = Wb; w2.M[2] = Wf; w2.M[3] = Wf;
        w2.dst0[0] = W2f; w2.dst0[1] = W2b;
        w2.selfSrc = 1;
        ghop_kernel<<<dim3(8, 8, 2), 256, 0, stream>>>(w2);
    }
    { // pack all 4 W matrices to fragment-contiguous bf16 hi/lo
        WPack p;
        p.w[0] = Wf; p.w[1] = W2f; p.w[2] = Wb; p.w[3] = W2b;
        for (int m = 0; m < 4; ++m) { p.hi[m] = Whi[m]; p.lo[m] = Wlo[m]; }
        wpack_kernel<<<dim3(1024, 4), 256, 0, stream>>>(p);
    }

    auto hopM_common = [&](HopM& a) {
        for (int m = 0; m < 4; ++m) { a.Ahi[m] = Whi[m]; a.Alo[m] = Wlo[m]; }
    };

    auto cell0 = [&](const float* xcur) {
        { // hops of h0 (MFMA) + hops of x (tiny fp32)
            HopM a = {}; hopM_common(a);
            a.src0 = h0; a.ncols0 = 1024; a.tiles0 = 16;
            for (int m = 0; m < 4; ++m) a.dst0[m] = HB[m];
            ghop_mfma<<<dim3(16, 4, 4), 256, 0, stream>>>(a);
            XHop xh; xh.M[0] = Wf; xh.M[1] = W2f; xh.M[2] = Wb; xh.M[3] = W2b;
            for (int m = 0; m < 4; ++m) xh.dst[m] = HXS[m];
            xhop_kernel<<<dim3(32, 4), 256, 0, stream>>>(xh, xcur);
        }
        Segs srz; srz.n = 10;
        srz.p[0] = xcur; srz.stride[0] = 1;  srz.len[0] = 1;  srz.wrow[0] = 0;
        srz.p[1] = h0;   srz.stride[1] = 64; srz.len[1] = 64; srz.wrow[1] = 1;
        for (int m = 0; m < 4; ++m) {
            srz.p[2 + 2 * m] = HXS[m]; srz.stride[2 + 2 * m] = 1;  srz.len[2 + 2 * m] = 1;
            srz.wrow[2 + 2 * m] = 65 * (m + 1);
            srz.p[3 + 2 * m] = HB[m];  srz.stride[3 + 2 * m] = 64; srz.len[3 + 2 * m] = 64;
            srz.wrow[3 + 2 * m] = 65 * (m + 1) + 1;
        }
        lin_rz_kernel<<<dim3(256, 2), 256, 0, stream>>>(srz, Wr0, br0, Wz0, bz0, h0, G, Zb);

        {
            HopM a = {}; hopM_common(a);
            a.src0 = G; a.ncols0 = 1024; a.tiles0 = 16;
            for (int m = 0; m < 4; ++m) a.dst0[m] = HG[m];
            ghop_mfma<<<dim3(16, 4, 4), 256, 0, stream>>>(a);
        }

        Segs sn; sn.n = 10;
        sn.p[0] = xcur; sn.stride[0] = 1;  sn.len[0] = 1;  sn.wrow[0] = 0;
        sn.p[1] = G;    sn.stride[1] = 64; sn.len[1] = 64; sn.wrow[1] = 1;
        for (int m = 0; m < 4; ++m) {
            sn.p[2 + 2 * m] = HXS[m]; sn.stride[2 + 2 * m] = 1;  sn.len[2 + 2 * m] = 1;
            sn.wrow[2 + 2 * m] = 65 * (m + 1);
            sn.p[3 + 2 * m] = HG[m];  sn.stride[3 + 2 * m] = 64; sn.len[3 + 2 * m] = 64;
            sn.wrow[3 + 2 * m] = 65 * (m + 1) + 1;
        }
        lin_n_kernel<<<dim3(256), 256, 0, stream>>>(sn, Wn0, bn0, Zb, h0, 0,
                                                    (const float*)nullptr, (const float*)nullptr,
                                                    (float*)nullptr, (float*)nullptr, 0);
    };

    auto cell1 = [&](int doProj, int t) {
        {
            HopM a = {}; hopM_common(a);
            a.src0 = h0; a.ncols0 = 1024; a.tiles0 = 16;
            a.src1 = h1; a.ncols1 = 1024;
            for (int m = 0; m < 4; ++m) { a.dst0[m] = HA[m]; a.dst1[m] = HB[m]; }
            ghop_mfma<<<dim3(32, 4, 4), 256, 0, stream>>>(a);
        }
        Segs srz; srz.n = 10;
        srz.p[0] = h0; srz.stride[0] = 64; srz.len[0] = 64; srz.wrow[0] = 0;
        srz.p[1] = h1; srz.stride[1] = 64; srz.len[1] = 64; srz.wrow[1] = 64;
        for (int m = 0; m < 4; ++m) {
            srz.p[2 + 2 * m] = HA[m]; srz.stride[2 + 2 * m] = 64; srz.len[2 + 2 * m] = 64;
            srz.wrow[2 + 2 * m] = 128 * (m + 1);
            srz.p[3 + 2 * m] = HB[m]; srz.stride[3 + 2 * m] = 64; srz.len[3 + 2 * m] = 64;
            srz.wrow[3 + 2 * m] = 128 * (m + 1) + 64;
        }
        lin_rz_kernel<<<dim3(256, 2), 256, 0, stream>>>(srz, Wr1, br1, Wz1, bz1, h1, G, Zb);

        {
            HopM a = {}; hopM_common(a);
            a.src0 = G; a.ncols0 = 1024; a.tiles0 = 16;
            for (int m = 0; m < 4; ++m) a.dst0[m] = HG[m];
            ghop_mfma<<<dim3(16, 4, 4), 256, 0, stream>>>(a);
        }

        Segs sn; sn.n = 10;
        sn.p[0] = h0; sn.stride[0] = 64; sn.len[0] = 64; sn.wrow[0] = 0;
        sn.p[1] = G;  sn.stride[1] = 64; sn.len[1] = 64; sn.wrow[1] = 64;
        for (int m = 0; m < 4; ++m) {
            sn.p[2 + 2 * m] = HA[m]; sn.stride[2 + 2 * m] = 64; sn.len[2 + 2 * m] = 64;
            sn.wrow[2 + 2 * m] = 128 * (m + 1);
            sn.p[3 + 2 * m] = HG[m]; sn.stride[3 + 2 * m] = 64; sn.len[3 + 2 * m] = 64;
            sn.wrow[3 + 2 * m] = 128 * (m + 1) + 64;
        }
        lin_n_kernel<<<dim3(256), 256, 0, stream>>>(sn, Wn1, bn1, Zb, h1, doProj,
                                                    Wp, bp, out, di, t);
    };

    for (int t = 0; t < T_IN; ++t) {
        cell0(xenc + (size_t)t * NB);
        cell1(0, 0);
    }
    for (int t = 0; t < T_OUT; ++t) {
        const float* xcur = (t == 0) ? (xenc + (size_t)(T_IN - 1) * NB) : di;
        cell0(xcur);
        cell1(1, t);
    }
}

// Round 4
// 5793.826 us; speedup vs baseline: 2.7283x; 1.0822x over previous
//
#include <hip/hip_runtime.h>
#include <math.h>

#define T_IN   12
#define T_OUT  12
#define NB     8192          /* 512 nodes x 16 batch, row id = n*16+b */
#define EPSV   1e-6f

typedef __attribute__((ext_vector_type(8))) short short8;
typedef __attribute__((ext_vector_type(4))) float floatx4;

// ---------------------------------------------------------------------------
// bf16 helpers. P-format: uint = (lo_bf16 << 16) | hi_bf16, value ~ hi + lo.
// ---------------------------------------------------------------------------
__device__ __forceinline__ unsigned short f2bf(float x) {     // RNE (setup packs)
    union { float f; unsigned u; } v; v.f = x;
    unsigned r = v.u + 0x7fffu + ((v.u >> 16) & 1u);
    return (unsigned short)(r >> 16);
}
__device__ __forceinline__ float bf2f(unsigned short h) {
    union { float f; unsigned u; } v; v.u = ((unsigned)h) << 16;
    return v.f;
}
__device__ __forceinline__ unsigned packbf(float v) {         // trunc split (hot path)
    unsigned u = __float_as_uint(v);
    unsigned hu = u & 0xffff0000u;
    float r = v - __uint_as_float(hu);
    unsigned ru = __float_as_uint(r);
    return (ru & 0xffff0000u) | (u >> 16);
}

// ---------------------------------------------------------------------------
// Descriptors
// ---------------------------------------------------------------------------
struct HopA {                    // fp32 setup GEMM (W^2 build)
    const float* M[4];
    float* dst0[4];
    int selfSrc;
};

struct HopM {                    // MFMA hop: Y[z] = M[z] @ X, X/Y in P-format
    const unsigned short* Ahi[4]; const unsigned short* Alo[4];
    const unsigned* src0; const unsigned* src1;
    unsigned* dst0[4]; unsigned* dst1[4];
    int tiles0;
};

struct XHop { const float* M[4]; float* dst[4]; };

struct WPack { const float* w[4]; unsigned short* hi[4]; unsigned short* lo[4]; };

struct LPack {                   // lin-weight fragment pack
    const float* W; unsigned short* hi; unsigned short* lo;
    int base[10]; int nseg;
};

struct LinA {                    // lin GEMM input descriptor
    const unsigned* seg[10]; int nseg;        // P-format (8192 x 64) segments
    const float* sx[5]; int sxrow[5]; int nsx; // scalar (len-1) segments, fp32
};

// ---------------------------------------------------------------------------
// Random-walk normalization
// ---------------------------------------------------------------------------
__global__ void sums_kernel(const float* __restrict__ A, float* __restrict__ rs,
                            float* __restrict__ cs) {
    int i = blockIdx.x;
    int t = threadIdx.x;
    __shared__ float s1[256], s2[256];
    float a = A[i * 512 + t] + A[i * 512 + t + 256];
    float b = A[t * 512 + i] + A[(t + 256) * 512 + i];
    s1[t] = a; s2[t] = b;
    __syncthreads();
    for (int off = 128; off > 0; off >>= 1) {
        if (t < off) { s1[t] += s1[t + off]; s2[t] += s2[t + off]; }
        __syncthreads();
    }
    if (t == 0) { rs[i] = s1[0]; cs[i] = s2[0]; }
}

__global__ void fill_kernel(const float* __restrict__ A, const float* __restrict__ rs,
                            const float* __restrict__ cs, float* __restrict__ Wf,
                            float* __restrict__ Wb) {
    int i = blockIdx.x;
    float irs = 1.0f / (rs[i] + EPSV);
    float ics = 1.0f / (cs[i] + EPSV);
    for (int j = threadIdx.x; j < 512; j += 256) {
        Wf[i * 512 + j] = A[i * 512 + j] * irs;
        Wb[i * 512 + j] = A[j * 512 + i] * ics;
    }
}

// Pre-transpose all encoder x slices: xenc[t][j*16+b] = x[b, t, j]
__global__ void xenc_kernel(const float* __restrict__ x, float* __restrict__ xenc) {
    int idx = blockIdx.x * 256 + threadIdx.x;
    if (idx >= T_IN * NB) return;
    int j = idx & 511;
    int b = (idx >> 9) & 15;
    int t = idx >> 13;
    xenc[t * NB + j * 16 + b] = x[(b * T_IN + t) * 512 + j];
}

// Pack W (512x512 fp32) into A-fragment-contiguous bf16 hi/lo (for hops)
__global__ void wpack_kernel(WPack a) {
    int z = blockIdx.y;
    int idx = blockIdx.x * 256 + threadIdx.x;   // 0..262143
    int m = idx >> 9, k = idx & 511;
    float x = a.w[z][idx];
    unsigned short h = f2bf(x);
    unsigned short l = f2bf(x - bf2f(h));
    int p = (((m >> 4) * 64 + (k >> 3)) * 16 + (m & 15)) * 8 + (k & 7);
    a.hi[z][p] = h;
    a.lo[z][p] = l;
}

// Pack lin weights (K x 64) into B-fragment order over len-64 segments.
// out idx = ((O*4 + nt)*16 + ln)*8 + j, O = s*8 + o8, src row = base[s]+o8*8+j.
__global__ void lpack_kernel(LPack p) {
    int idx = blockIdx.x * 256 + threadIdx.x;
    if (idx >= p.nseg * 4096) return;
    int j = idx & 7, ln = (idx >> 3) & 15, ntl = (idx >> 7) & 3, O = idx >> 9;
    int s = O >> 3, o8 = O & 7;
    int row = p.base[s] + o8 * 8 + j;
    int col = ntl * 16 + ln;
    float v = p.W[(size_t)row * 64 + col];
    unsigned short h = f2bf(v);
    p.hi[idx] = h;
    p.lo[idx] = f2bf(v - bf2f(h));
}

// ---------------------------------------------------------------------------
// fp32 GEMM for the setup-only W^2 build. 64x64 tile, 4x4 micro.
// ---------------------------------------------------------------------------
__global__ __launch_bounds__(256) void ghop_kernel(HopA a) {
    int z = blockIdx.z;
    const float* Wm = a.M[z];
    const float* X = Wm;
    float* Y = a.dst0[z];
    int ncols = 512;
    int col0 = blockIdx.x * 64;
    int row0 = blockIdx.y * 64;
    int tid = threadIdx.x;
    int tx = tid & 15, ty = tid >> 4;
    int kkA = tid & 15, rrA = tid >> 4;
    int ccB = tid & 63, kkB = tid >> 6;

    __shared__ float As[16][68], Bs[16][68];
    float acc[4][4] = {};

    const float* wp = Wm + (row0 + rrA) * 512 + kkA;
    const float* xp = X + (size_t)(col0 + ccB) + (size_t)kkB * 512;

    float ra[4], rb[4];
#pragma unroll
    for (int p = 0; p < 4; ++p) ra[p] = wp[p * 16 * 512];
#pragma unroll
    for (int p = 0; p < 4; ++p) rb[p] = xp[(size_t)(p * 4) * 512];

    for (int k0 = 0; k0 < 512; k0 += 16) {
#pragma unroll
        for (int p = 0; p < 4; ++p) As[kkA][rrA + p * 16] = ra[p];
#pragma unroll
        for (int p = 0; p < 4; ++p) Bs[kkB + p * 4][ccB] = rb[p];
        __syncthreads();
        if (k0 + 16 < 512) {
            int kn = k0 + 16;
#pragma unroll
            for (int p = 0; p < 4; ++p) ra[p] = wp[p * 16 * 512 + kn];
#pragma unroll
            for (int p = 0; p < 4; ++p) rb[p] = xp[(size_t)(kn + p * 4) * 512];
        }
#pragma unroll
        for (int k = 0; k < 16; ++k) {
            const float4 a4 = *(const float4*)&As[k][ty * 4];
            const float4 b4 = *(const float4*)&Bs[k][tx * 4];
            float av[4] = { a4.x, a4.y, a4.z, a4.w };
            float bv[4] = { b4.x, b4.y, b4.z, b4.w };
#pragma unroll
            for (int i = 0; i < 4; ++i)
#pragma unroll
                for (int j = 0; j < 4; ++j)
                    acc[i][j] = fmaf(av[i], bv[j], acc[i][j]);
        }
        __syncthreads();
    }

    int colw = col0 + tx * 4;
#pragma unroll
    for (int i = 0; i < 4; ++i) {
        int row = row0 + ty * 4 + i;
        *(float4*)&Y[(size_t)row * ncols + colw] =
            make_float4(acc[i][0], acc[i][1], acc[i][2], acc[i][3]);
    }
}

// ---------------------------------------------------------------------------
// MFMA hop GEMM: Y[z](512x1024) = M[z](512x512) @ X(512x1024); X,Y P-format.
// Split-bf16 3-pass. Block 128m x 64n x 32k, 4 waves, wave 64m x 32n.
// ---------------------------------------------------------------------------
__global__ __launch_bounds__(256) void ghop_mfma(HopM a) {
    int z = blockIdx.z;
    int nt = blockIdx.x;
    const unsigned* X; unsigned* Y; int c0;
    if (nt < a.tiles0) { X = a.src0; Y = a.dst0[z]; c0 = nt * 64; }
    else { X = a.src1; Y = a.dst1[z]; c0 = (nt - a.tiles0) * 64; }
    const unsigned short* Ahi = a.Ahi[z];
    const unsigned short* Alo = a.Alo[z];
    int bm = blockIdx.y * 128;

    __shared__ unsigned short Bhi_s[64][40];
    __shared__ unsigned short Blo_s[64][40];

    int tid = threadIdx.x;
    int lane = tid & 63;
    int w = tid >> 6;
    int wm = (w & 1) * 64;
    int wn = (w >> 1) * 32;
    int ln = lane & 15;
    int quad = lane >> 4;
    int sc = tid & 63;
    int skh = tid >> 6;

    floatx4 acc[4][2];
#pragma unroll
    for (int mi = 0; mi < 4; ++mi)
#pragma unroll
        for (int ci = 0; ci < 2; ++ci) acc[mi][ci] = (floatx4)0.0f;

    const unsigned* xbase = X + c0 + sc;
    int mtb = (bm + wm) >> 4;

    unsigned uv[8];
#pragma unroll
    for (int j = 0; j < 8; ++j)
        uv[j] = xbase[(size_t)(skh * 8 + j) * 1024];

    for (int k0 = 0; k0 < 512; k0 += 32) {
        short8 h8, l8;
#pragma unroll
        for (int j = 0; j < 8; ++j) {
            h8[j] = (short)(uv[j] & 0xffffu);
            l8[j] = (short)(uv[j] >> 16);
        }
        __syncthreads();
        *(short8*)&Bhi_s[sc][skh * 8] = h8;
        *(short8*)&Blo_s[sc][skh * 8] = l8;
        __syncthreads();
        if (k0 + 32 < 512) {
            int kn = k0 + 32;
#pragma unroll
            for (int j = 0; j < 8; ++j)
                uv[j] = xbase[(size_t)(kn + skh * 8 + j) * 1024];
        }
        short8 bh[2], bl[2];
#pragma unroll
        for (int ci = 0; ci < 2; ++ci) {
            bh[ci] = *(const short8*)&Bhi_s[wn + ci * 16 + ln][quad * 8];
            bl[ci] = *(const short8*)&Blo_s[wn + ci * 16 + ln][quad * 8];
        }
        int kob = (k0 >> 3) + quad;
#pragma unroll
        for (int mi = 0; mi < 4; ++mi) {
            size_t aoff = ((size_t)((mtb + mi) * 64 + kob) * 16 + ln) * 8;
            short8 Ah = *(const short8*)(Ahi + aoff);
            short8 Al = *(const short8*)(Alo + aoff);
#pragma unroll
            for (int ci = 0; ci < 2; ++ci) {
                acc[mi][ci] = __builtin_amdgcn_mfma_f32_16x16x32_bf16(Ah, bh[ci], acc[mi][ci], 0, 0, 0);
                acc[mi][ci] = __builtin_amdgcn_mfma_f32_16x16x32_bf16(Ah, bl[ci], acc[mi][ci], 0, 0, 0);
                acc[mi][ci] = __builtin_amdgcn_mfma_f32_16x16x32_bf16(Al, bh[ci], acc[mi][ci], 0, 0, 0);
            }
        }
    }

#pragma unroll
    for (int mi = 0; mi < 4; ++mi) {
#pragma unroll
        for (int ci = 0; ci < 2; ++ci) {
            int mrow = bm + wm + mi * 16 + quad * 4;
            int col = c0 + wn + ci * 16 + ln;
#pragma unroll
            for (int r = 0; r < 4; ++r)
                Y[(size_t)(mrow + r) * 1024 + col] = packbf(acc[mi][ci][r]);
        }
    }
}

// ---------------------------------------------------------------------------
// Tiny x-hop (fp32): dst[z][m*16+c] = sum_k M[z][m][k] * xv[k*16+c]
// ---------------------------------------------------------------------------
__global__ void xhop_kernel(XHop a, const float* __restrict__ xv) {
    int z = blockIdx.y;
    const float* M = a.M[z];
    int m = blockIdx.x * 16 + (threadIdx.x >> 4);
    int c = threadIdx.x & 15;
    const float* wrow = M + (size_t)m * 512;
    float s = 0.0f;
#pragma unroll 4
    for (int k = 0; k < 512; ++k)
        s = fmaf(wrow[k], xv[k * 16 + c], s);
    a.dst[z][m * 16 + c] = s;
}

// ---------------------------------------------------------------------------
// MFMA lin core: wave computes 16 rows x 64 cols; A = P-format activations,
// B = pre-packed split weights (global, no LDS). 3-pass split-bf16.
// ---------------------------------------------------------------------------
__device__ __forceinline__ void lin_core(const LinA& a,
        const unsigned short* __restrict__ Bh, const unsigned short* __restrict__ Bl,
        int row0, int ln, int quad, floatx4 acc[4]) {
    for (int s = 0; s < a.nseg; ++s) {
        const unsigned* ap = a.seg[s] + (size_t)(row0 + ln) * 64 + quad * 8;
#pragma unroll
        for (int hh = 0; hh < 2; ++hh) {
            unsigned u[8];
            *(uint4*)&u[0] = *(const uint4*)(ap + hh * 32);
            *(uint4*)&u[4] = *(const uint4*)(ap + hh * 32 + 4);
            short8 Ah, Al;
#pragma unroll
            for (int j = 0; j < 8; ++j) {
                Ah[j] = (short)(u[j] & 0xffffu);
                Al[j] = (short)(u[j] >> 16);
            }
            int O = s * 8 + hh * 4 + quad;
#pragma unroll
            for (int ci = 0; ci < 4; ++ci) {
                size_t boff = ((size_t)(O * 4 + ci) * 16 + ln) * 8;
                short8 B1 = *(const short8*)(Bh + boff);
                short8 B2 = *(const short8*)(Bl + boff);
                acc[ci] = __builtin_amdgcn_mfma_f32_16x16x32_bf16(Ah, B1, acc[ci], 0, 0, 0);
                acc[ci] = __builtin_amdgcn_mfma_f32_16x16x32_bf16(Al, B1, acc[ci], 0, 0, 0);
                acc[ci] = __builtin_amdgcn_mfma_f32_16x16x32_bf16(Ah, B2, acc[ci], 0, 0, 0);
            }
        }
    }
}

__device__ __forceinline__ void lin_scalar(const LinA& a, const float* __restrict__ WO,
        int row0, int ln, int quad, floatx4 acc[4]) {
    for (int t = 0; t < a.nsx; ++t) {
        const float* wr = WO + (size_t)a.sxrow[t] * 64;
        const float* sv = a.sx[t] + row0 + quad * 4;
#pragma unroll
        for (int rr = 0; rr < 4; ++rr) {
            float v = sv[rr];
#pragma unroll
            for (int ci = 0; ci < 4; ++ci)
                acc[ci][rr] = fmaf(v, wr[ci * 16 + ln], acc[ci][rr]);
        }
    }
}

__device__ __forceinline__ float sigmoid_fast(float x) {
    return 1.0f / (1.0f + __expf(-x));
}
__device__ __forceinline__ float tanh_fast(float x) {
    float e = __expf(2.0f * x);
    return 1.0f - 2.0f / (e + 1.0f);
}

// r/z gates (MFMA): grid (128, 2). y==0: GP = pack(sigmoid(pre_r)*h); y==1: Z = sigmoid.
__global__ __launch_bounds__(256) void lin_rz_mfma(
    LinA a,
    const unsigned short* Wrh, const unsigned short* Wrl, const float* WrO, const float* br,
    const unsigned short* Wzh, const unsigned short* Wzl, const float* WzO, const float* bz,
    const float* __restrict__ h, unsigned* __restrict__ GP, float* __restrict__ Z) {
    int w = threadIdx.x >> 6, lane = threadIdx.x & 63;
    int ln = lane & 15, quad = lane >> 4;
    int row0 = blockIdx.x * 64 + w * 16;
    int gate = blockIdx.y;
    const unsigned short* Bh = gate ? Wzh : Wrh;
    const unsigned short* Bl = gate ? Wzl : Wrl;
    const float* WO = gate ? WzO : WrO;
    const float* bias = gate ? bz : br;
    floatx4 acc[4];
#pragma unroll
    for (int ci = 0; ci < 4; ++ci) acc[ci] = (floatx4)0.0f;
    lin_core(a, Bh, Bl, row0, ln, quad, acc);
    lin_scalar(a, WO, row0, ln, quad, acc);
#pragma unroll
    for (int ci = 0; ci < 4; ++ci) {
        int col = ci * 16 + ln;
        float bv = bias[col];
#pragma unroll
        for (int rr = 0; rr < 4; ++rr) {
            int row = row0 + quad * 4 + rr;
            size_t idx = (size_t)row * 64 + col;
            float sg = sigmoid_fast(acc[ci][rr] + bv);
            if (gate == 0) GP[idx] = packbf(sg * h[idx]);
            else Z[idx] = sg;
        }
    }
}

// n gate + GRU update (MFMA): writes h fp32 + hP; optional fused projection.
__global__ __launch_bounds__(256) void lin_n_mfma(
    LinA a, const unsigned short* Wnh, const unsigned short* Wnl,
    const float* WnO, const float* bn,
    const float* __restrict__ Zb, float* __restrict__ h, unsigned* __restrict__ hP,
    int doProj, const float* __restrict__ Wp, const float* __restrict__ bp,
    float* __restrict__ out, float* __restrict__ di, int t) {
    int w = threadIdx.x >> 6, lane = threadIdx.x & 63;
    int ln = lane & 15, quad = lane >> 4;
    int row0 = blockIdx.x * 64 + w * 16;
    floatx4 acc[4];
#pragma unroll
    for (int ci = 0; ci < 4; ++ci) acc[ci] = (floatx4)0.0f;
    lin_core(a, Wnh, Wnl, row0, ln, quad, acc);
    lin_scalar(a, WnO, row0, ln, quad, acc);
    float p[4] = {0.0f, 0.0f, 0.0f, 0.0f};
#pragma unroll
    for (int ci = 0; ci < 4; ++ci) {
        int col = ci * 16 + ln;
        float bv = bn[col];
        float wpv = doProj ? Wp[col] : 0.0f;
#pragma unroll
        for (int rr = 0; rr < 4; ++rr) {
            int row = row0 + quad * 4 + rr;
            size_t idx = (size_t)row * 64 + col;
            float nn = tanh_fast(acc[ci][rr] + bv);
            float z = Zb[idx];
            float hv = h[idx];
            float o = (1.0f - z) * hv + z * nn;
            h[idx] = o;
            hP[idx] = packbf(o);
            p[rr] = fmaf(o, wpv, p[rr]);
        }
    }
    if (doProj) {
#pragma unroll
        for (int rr = 0; rr < 4; ++rr) {
            p[rr] += __shfl_xor(p[rr], 1, 64);
            p[rr] += __shfl_xor(p[rr], 2, 64);
            p[rr] += __shfl_xor(p[rr], 4, 64);
            p[rr] += __shfl_xor(p[rr], 8, 64);
        }
        if (ln == 0) {
            float bpv = bp[0];
#pragma unroll
            for (int rr = 0; rr < 4; ++rr) {
                int row = row0 + quad * 4 + rr;
                float y = p[rr] + bpv;
                int n = row >> 4, b = row & 15;
                out[(b * T_OUT + t) * 512 + n] = y;
                di[row] = y;
            }
        }
    }
}

// ---------------------------------------------------------------------------
extern "C" void kernel_launch(void* const* d_in, const int* in_sizes, int n_in,
                              void* d_out, int out_size, void* d_ws, size_t ws_size,
                              hipStream_t stream) {
    (void)in_sizes; (void)n_in; (void)out_size; (void)ws_size;
    const float* x   = (const float*)d_in[0];
    const float* A   = (const float*)d_in[1];
    const float* Wr0 = (const float*)d_in[2];  const float* br0 = (const float*)d_in[3];
    const float* Wz0 = (const float*)d_in[4];  const float* bz0 = (const float*)d_in[5];
    const float* Wn0 = (const float*)d_in[6];  const float* bn0 = (const float*)d_in[7];
    const float* Wr1 = (const float*)d_in[8];  const float* br1 = (const float*)d_in[9];
    const float* Wz1 = (const float*)d_in[10]; const float* bz1 = (const float*)d_in[11];
    const float* Wn1 = (const float*)d_in[12]; const float* bn1 = (const float*)d_in[13];
    const float* Wp  = (const float*)d_in[14]; const float* bp  = (const float*)d_in[15];
    float* out = (float*)d_out;

    float* ws = (float*)d_ws;
    size_t off = 0;
    auto alloc = [&](size_t nf) { float* p = ws + off; off += nf; return p; };
    float* Wf  = alloc(262144); float* Wb  = alloc(262144);
    float* W2f = alloc(262144); float* W2b = alloc(262144);
    float* rs  = alloc(512);    float* cs  = alloc(512);
    float* xenc = alloc((size_t)T_IN * NB);
    // hop A-operand packs (bf16 hi/lo, fragment order): 4 mats
    unsigned short* Whi[4]; unsigned short* Wlo[4];
    for (int m = 0; m < 4; ++m) Whi[m] = (unsigned short*)alloc(131072);
    for (int m = 0; m < 4; ++m) Wlo[m] = (unsigned short*)alloc(131072);
    // P-format activations (8192 x 64 uints each)
    unsigned* HA_P[4]; unsigned* HB_P[4]; unsigned* HG_P[4];
    for (int m = 0; m < 4; ++m) HA_P[m] = (unsigned*)alloc(524288);
    for (int m = 0; m < 4; ++m) HB_P[m] = (unsigned*)alloc(524288);
    for (int m = 0; m < 4; ++m) HG_P[m] = (unsigned*)alloc(524288);
    unsigned* GP  = (unsigned*)alloc(524288);
    unsigned* h0P = (unsigned*)alloc(524288);
    unsigned* h1P = (unsigned*)alloc(524288);
    float* Z  = alloc(524288);
    float* h0 = alloc(524288);
    float* h1 = alloc(524288);
    float* HXS[4];
    for (int m = 0; m < 4; ++m) HXS[m] = alloc(8192);
    float* di = alloc(8192);
    // lin weight packs: gate order r0,z0,n0 (nseg=5), r1,z1,n1 (nseg=10)
    unsigned short* LWh[6]; unsigned short* LWl[6];
    for (int g = 0; g < 3; ++g) { LWh[g] = (unsigned short*)alloc(10240); LWl[g] = (unsigned short*)alloc(10240); }
    for (int g = 3; g < 6; ++g) { LWh[g] = (unsigned short*)alloc(20480); LWl[g] = (unsigned short*)alloc(20480); }

    hipMemsetAsync(h0, 0, 524288 * sizeof(float), stream);
    hipMemsetAsync(h1, 0, 524288 * sizeof(float), stream);
    hipMemsetAsync(h0P, 0, 524288 * sizeof(unsigned), stream);
    hipMemsetAsync(h1P, 0, 524288 * sizeof(unsigned), stream);

    xenc_kernel<<<dim3((T_IN * NB) / 256), 256, 0, stream>>>(x, xenc);
    sums_kernel<<<dim3(512), 256, 0, stream>>>(A, rs, cs);
    fill_kernel<<<dim3(512), 256, 0, stream>>>(A, rs, cs, Wf, Wb);

    { // W2f = Wf@Wf, W2b = Wb@Wb (fp32, setup only)
        HopA w2 = {};
        w2.M[0] = Wf; w2.M[1] = Wb;
        w2.dst0[0] = W2f; w2.dst0[1] = W2b;
        w2.selfSrc = 1;
        ghop_kernel<<<dim3(8, 8, 2), 256, 0, stream>>>(w2);
    }
    { // pack hop A-operands
        WPack p;
        p.w[0] = Wf; p.w[1] = W2f; p.w[2] = Wb; p.w[3] = W2b;
        for (int m = 0; m < 4; ++m) { p.hi[m] = Whi[m]; p.lo[m] = Wlo[m]; }
        wpack_kernel<<<dim3(1024, 4), 256, 0, stream>>>(p);
    }
    { // pack lin weights
        const float* WG[6] = { Wr0, Wz0, Wn0, Wr1, Wz1, Wn1 };
        for (int g = 0; g < 6; ++g) {
            LPack p = {};
            p.W = WG[g]; p.hi = LWh[g]; p.lo = LWl[g];
            if (g < 3) { p.nseg = 5;  for (int s = 0; s < 5; ++s)  p.base[s] = 65 * s + 1; }
            else       { p.nseg = 10; for (int s = 0; s < 10; ++s) p.base[s] = 64 * s; }
            lpack_kernel<<<dim3((p.nseg * 4096 + 255) / 256), 256, 0, stream>>>(p);
        }
    }

    auto hopcom = [&](HopM& a) {
        for (int m = 0; m < 4; ++m) { a.Ahi[m] = Whi[m]; a.Alo[m] = Wlo[m]; }
    };

    auto cell0 = [&](const float* xcur) {
        {
            HopM a = {}; hopcom(a);
            a.src0 = h0P; a.tiles0 = 16;
            for (int m = 0; m < 4; ++m) a.dst0[m] = HB_P[m];
            ghop_mfma<<<dim3(16, 4, 4), 256, 0, stream>>>(a);
            XHop xh; xh.M[0] = Wf; xh.M[1] = W2f; xh.M[2] = Wb; xh.M[3] = W2b;
            for (int m = 0; m < 4; ++m) xh.dst[m] = HXS[m];
            xhop_kernel<<<dim3(32, 4), 256, 0, stream>>>(xh, xcur);
        }
        LinA la = {};
        la.nseg = 5;
        la.seg[0] = h0P;
        for (int m = 0; m < 4; ++m) la.seg[1 + m] = HB_P[m];
        la.nsx = 5;
        la.sx[0] = xcur; la.sxrow[0] = 0;
        for (int m = 0; m < 4; ++m) { la.sx[1 + m] = HXS[m]; la.sxrow[1 + m] = 65 * (m + 1); }
        lin_rz_mfma<<<dim3(128, 2), 256, 0, stream>>>(la, LWh[0], LWl[0], Wr0, br0,
                                                      LWh[1], LWl[1], Wz0, bz0, h0, GP, Z);
        {
            HopM a = {}; hopcom(a);
            a.src0 = GP; a.tiles0 = 16;
            for (int m = 0; m < 4; ++m) a.dst0[m] = HG_P[m];
            ghop_mfma<<<dim3(16, 4, 4), 256, 0, stream>>>(a);
        }
        LinA lb = la;
        lb.seg[0] = GP;
        for (int m = 0; m < 4; ++m) lb.seg[1 + m] = HG_P[m];
        lin_n_mfma<<<dim3(128), 256, 0, stream>>>(lb, LWh[2], LWl[2], Wn0, bn0, Z, h0, h0P,
                                                  0, (const float*)nullptr, (const float*)nullptr,
                                                  (float*)nullptr, (float*)nullptr, 0);
    };

    auto cell1 = [&](int doProj, int t) {
        {
            HopM a = {}; hopcom(a);
            a.src0 = h0P; a.tiles0 = 16;
            a.src1 = h1P;
            for (int m = 0; m < 4; ++m) { a.dst0[m] = HA_P[m]; a.dst1[m] = HB_P[m]; }
            ghop_mfma<<<dim3(32, 4, 4), 256, 0, stream>>>(a);
        }
        LinA la = {};
        la.nseg = 10; la.nsx = 0;
        la.seg[0] = h0P; la.seg[1] = h1P;
        for (int m = 0; m < 4; ++m) { la.seg[2 + 2 * m] = HA_P[m]; la.seg[3 + 2 * m] = HB_P[m]; }
        lin_rz_mfma<<<dim3(128, 2), 256, 0, stream>>>(la, LWh[3], LWl[3], Wr1, br1,
                                                      LWh[4], LWl[4], Wz1, bz1, h1, GP, Z);
        {
            HopM a = {}; hopcom(a);
            a.src0 = GP; a.tiles0 = 16;
            for (int m = 0; m < 4; ++m) a.dst0[m] = HG_P[m];
            ghop_mfma<<<dim3(16, 4, 4), 256, 0, stream>>>(a);
        }
        LinA lb = la;
        lb.seg[1] = GP;
        for (int m = 0; m < 4; ++m) lb.seg[3 + 2 * m] = HG_P[m];
        lin_n_mfma<<<dim3(128), 256, 0, stream>>>(lb, LWh[5], LWl[5], Wn1, bn1, Z, h1, h1P,
                                                  doProj, Wp, bp, out, di, t);
    };

    for (int t = 0; t < T_IN; ++t) {
        cell0(xenc + (size_t)t * NB);
        cell1(0, 0);
    }
    for (int t = 0; t < T_OUT; ++t) {
        const float* xcur = (t == 0) ? (xenc + (size_t)(T_IN - 1) * NB) : di;
        cell0(xcur);
        cell1(1, t);
    }
}